// Round 1
// baseline (89.343 us; speedup 1.0000x reference)
//
#include <hip/hip_runtime.h>

// Reference: k_full = zero-pad(key[..., :64] -> 128), same for value.
// Shapes: [8, 8, 4096, 128] f32.  Row = 128 f32 = 32 float4.
// For output float4 index i: col = i & 31. If col < 16, out[i] = in[i]
// (layouts identical in the copied region), else out[i] = 0.

__global__ __launch_bounds__(256) void kvcache_pad_kernel(
    const float4* __restrict__ k_in,
    const float4* __restrict__ v_in,
    float4* __restrict__ out,
    long n_f4) {  // float4 elements per tensor
  const float4 zero = make_float4(0.f, 0.f, 0.f, 0.f);
  long i = (long)blockIdx.x * blockDim.x + threadIdx.x;
  const long stride = (long)gridDim.x * blockDim.x;
  for (; i < n_f4; i += stride) {
    const bool copy = (i & 31) < 16;
    float4 kv = copy ? k_in[i] : zero;
    float4 vv = copy ? v_in[i] : zero;
    out[i] = kv;
    out[n_f4 + i] = vv;
  }
}

extern "C" void kernel_launch(void* const* d_in, const int* in_sizes, int n_in,
                              void* d_out, int out_size, void* d_ws, size_t ws_size,
                              hipStream_t stream) {
  const float4* k_in = (const float4*)d_in[0];
  const float4* v_in = (const float4*)d_in[1];
  float4* out = (float4*)d_out;

  // in_sizes[0] = 8*8*4096*128 = 33554432 floats -> 8388608 float4 per tensor
  const long n_f4 = (long)in_sizes[0] / 4;

  const int block = 256;
  const int grid = 2048;  // 256 CU x 8 blocks/CU; grid-stride the rest
  kvcache_pad_kernel<<<grid, block, 0, stream>>>(k_in, v_in, out, n_f4);
}

// Round 2
// 75.830 us; speedup vs baseline: 1.1782x; 1.1782x over previous
//
#include <hip/hip_runtime.h>

// k_full = zero-pad(key[..., :64] -> 128), same for value. [8,8,4096,128] f32.
// Row = 128 f32 = 32 float4; first 16 f4 copied (input index == output index),
// last 16 f4 zeroed. Thread j owns half-row f4 slot: o = (j>>4)*32 + (j&15).
// All lanes fully active: 1 useful load + 2 stores per tensor. Nontemporal:
// data is touched exactly once (streaming), skip L2 pollution.

typedef float f4_t __attribute__((ext_vector_type(4)));

__global__ __launch_bounds__(256) void kvcache_pad_kernel(
    const f4_t* __restrict__ k_in,
    const f4_t* __restrict__ v_in,
    f4_t* __restrict__ out,
    long n_f4,      // f4 elements per output tensor (8388608)
    long n_half) {  // f4 elements in copied halves per tensor (4194304)
  const f4_t zero = (f4_t)(0.f);
  long j = (long)blockIdx.x * blockDim.x + threadIdx.x;
  const long stride = (long)gridDim.x * blockDim.x;
  for (; j < n_half; j += stride) {
    const long o = ((j >> 4) << 5) | (j & 15);
    f4_t kv = __builtin_nontemporal_load(&k_in[o]);
    f4_t vv = __builtin_nontemporal_load(&v_in[o]);
    __builtin_nontemporal_store(kv, &out[o]);
    __builtin_nontemporal_store(zero, &out[o + 16]);
    __builtin_nontemporal_store(vv, &out[n_f4 + o]);
    __builtin_nontemporal_store(zero, &out[n_f4 + o + 16]);
  }
}

extern "C" void kernel_launch(void* const* d_in, const int* in_sizes, int n_in,
                              void* d_out, int out_size, void* d_ws, size_t ws_size,
                              hipStream_t stream) {
  const f4_t* k_in = (const f4_t*)d_in[0];
  const f4_t* v_in = (const f4_t*)d_in[1];
  f4_t* out = (f4_t*)d_out;

  const long n_f4 = (long)in_sizes[0] / 4;  // 8388608
  const long n_half = n_f4 / 2;             // 4194304

  const int block = 256;
  const int grid = 2048;  // 256 CU x 8 blocks/CU; grid-stride (8 iters/thread)
  kvcache_pad_kernel<<<grid, block, 0, stream>>>(k_in, v_in, out, n_f4, n_half);
}